// Round 9
// baseline (262.045 us; speedup 1.0000x reference)
//
#include <hip/hip_runtime.h>
#include <stdint.h>

// out[b] = argmax_k cos(h_b, A_k), int32, first-index ties.
// prep: rn[k]=1/max(||A_k||,eps); a8/h8 = int8(round(x_norm * 127/0.26)) row-major.
// score: i8 MFMA 16x16x64 screen (exact int accum, fixed scale -> rank by raw
//        int dot); per-row top-3 per block -> cand[4096][32][3].
// refine: exact fp32 rescore of top-8 of 96 candidates per row.

#define DIM 512
#define B_ROWS 4096
#define K_ROWS 32768
#define BT 128
#define KT 128
#define NKT (K_ROWS / KT)    // 256
#define KSLOTS 32            // grid = 32*32 = 1024 = 4 blocks/CU, 8 k-tiles each
#define NCHUNK 4             // D chunks of 128 bytes (i8)
#define QSCALE (127.0f / 0.26f)

typedef __attribute__((ext_vector_type(4))) float fx4;
typedef __attribute__((ext_vector_type(4))) int int4v;
typedef unsigned long long u64;

__device__ __forceinline__ uint32_t ford(float s) {
    uint32_t u = __float_as_uint(s);
    return u ^ ((uint32_t)((int32_t)u >> 31) | 0x80000000u);
}
__device__ __forceinline__ u64 umax64(u64 a, u64 b) { return a > b ? a : b; }
__device__ __forceinline__ u64 umin64(u64 a, u64 b) { return a < b ? a : b; }
__device__ __forceinline__ uint32_t umax32(uint32_t a, uint32_t b) { return a > b ? a : b; }
__device__ __forceinline__ uint32_t umin32(uint32_t a, uint32_t b) { return a < b ? a : b; }

__device__ __forceinline__ int q8(float x, float qs) {
    int v = __float2int_rn(x * qs);
    return v < -127 ? -127 : (v > 127 ? 127 : v);
}

// Fused prep: one wave per row. Blocks 0..8191 -> A rows (rn + a8);
// blocks 8192..9215 -> h rows (h8). Row-major i8, 8 bytes/lane.
__global__ __launch_bounds__(256) void prep_kernel(const float* __restrict__ A,
                                                   const float* __restrict__ h,
                                                   char* __restrict__ a8,
                                                   char* __restrict__ h8,
                                                   float* __restrict__ rn) {
    const int lane = threadIdx.x & 63, wid = threadIdx.x >> 6;
    const bool isA = blockIdx.x < 8192;
    const int row = (isA ? blockIdx.x : blockIdx.x - 8192) * 4 + wid;
    const float* src = (isA ? A : h) + (size_t)row * DIM;
    char* dst = (isA ? a8 : h8) + (size_t)row * DIM;

    const fx4* p = (const fx4*)src;
    fx4 a = p[lane * 2], b = p[lane * 2 + 1];
    float ss = a[0]*a[0] + a[1]*a[1] + a[2]*a[2] + a[3]*a[3]
             + b[0]*b[0] + b[1]*b[1] + b[2]*b[2] + b[3]*b[3];
    #pragma unroll
    for (int off = 32; off > 0; off >>= 1) ss += __shfl_xor(ss, off, 64);
    float r = 1.0f / fmaxf(sqrtf(ss), 1e-8f);
    if (isA && lane == 0) rn[row] = r;

    float qs = r * QSCALE;
    int v0 = q8(a[0], qs), v1 = q8(a[1], qs), v2 = q8(a[2], qs), v3 = q8(a[3], qs);
    int v4 = q8(b[0], qs), v5 = q8(b[1], qs), v6 = q8(b[2], qs), v7 = q8(b[3], qs);
    uint32_t lo = (uint32_t)(v0 & 255) | ((uint32_t)(v1 & 255) << 8)
                | ((uint32_t)(v2 & 255) << 16) | ((uint32_t)(v3 & 255) << 24);
    uint32_t hi = (uint32_t)(v4 & 255) | ((uint32_t)(v5 & 255) << 8)
                | ((uint32_t)(v6 & 255) << 16) | ((uint32_t)(v7 & 255) << 24);
    *reinterpret_cast<uint2*>(dst + lane * 8) = make_uint2(lo, hi);
}

typedef __attribute__((address_space(3))) uint32_t lds_u32;
typedef __attribute__((address_space(1))) const uint32_t g_u32;

__global__ __launch_bounds__(256, 4) void score_kernel(
    const char* __restrict__ h8, const char* __restrict__ a8,
    u64* __restrict__ cand)
{
    // per-chunk tiles: hf [128 rows][128 B] @0, af @16384; union: u32 cl[128][33]
    __shared__ __attribute__((aligned(16))) char smem[33792];
    char* hf = smem;
    char* af = smem + 16384;

    const int t = threadIdx.x, lane = t & 63, wid = t >> 6;
    const int wm = wid >> 1, wn = wid & 1;
    const int lr = lane & 15, q = lane >> 4;
    const int btile = blockIdx.x >> 5, kslot = blockIdx.x & 31;
    const int b0 = btile * BT;

    const int srow = lane >> 3;           // row within 8-row staging group
    const int scol = (lane & 7) ^ srow;   // source granule (XOR swizzle)
    const int s7 = lr & 7;
    const int sw0 = (q ^ s7) * 16;        // K-half 0: source granule q
    const int sw1 = ((4 + q) ^ s7) * 16;  // K-half 1: source granule 4+q

    const char* hsrc = h8 + (size_t)b0 * DIM;

    uint32_t v1[16], v2[16];   // per-thread top-2 per C-row, (ord&~63)|meta
    #pragma unroll
    for (int s = 0; s < 16; s++) { v1[s] = 0u; v2[s] = 0u; }

    int it = 0;
    for (int kt = kslot; kt < NKT; kt += KSLOTS, it++) {   // exactly 8 iters
        const int k0 = kt * KT;
        const char* asrc = a8 + (size_t)k0 * DIM;

        int4v acc[4][4];
        #pragma unroll
        for (int mi = 0; mi < 4; mi++)
            #pragma unroll
            for (int ni = 0; ni < 4; ni++)
                acc[mi][ni] = (int4v){0, 0, 0, 0};

        for (int dc = 0; dc < NCHUNK; dc++) {
            __syncthreads();
            #pragma unroll
            for (int i = 0; i < 4; i++) {
                int issue = wid * 4 + i;
                size_t roff = (size_t)(issue * 8 + srow) * DIM + dc * 128 + scol * 16;
                __builtin_amdgcn_global_load_lds((g_u32*)(hsrc + roff),
                    (lds_u32*)(hf + issue * 1024), 16, 0, 0);
                __builtin_amdgcn_global_load_lds((g_u32*)(asrc + roff),
                    (lds_u32*)(af + issue * 1024), 16, 0, 0);
            }
            __syncthreads();

            int4v af0[4], af1[4];
            #pragma unroll
            for (int ni = 0; ni < 4; ni++) {
                const char* base = af + (wn * 64 + ni * 16 + lr) * 128;
                af0[ni] = *reinterpret_cast<const int4v*>(base + sw0);
                af1[ni] = *reinterpret_cast<const int4v*>(base + sw1);
            }
            #pragma unroll
            for (int mi = 0; mi < 4; mi++) {
                const char* base = hf + (wm * 64 + mi * 16 + lr) * 128;
                int4v h0 = *reinterpret_cast<const int4v*>(base + sw0);
                int4v h1 = *reinterpret_cast<const int4v*>(base + sw1);
                #pragma unroll
                for (int ni = 0; ni < 4; ni++) {
                    acc[mi][ni] = __builtin_amdgcn_mfma_i32_16x16x64_i8(h0, af0[ni], acc[mi][ni], 0, 0, 0);
                    acc[mi][ni] = __builtin_amdgcn_mfma_i32_16x16x64_i8(h1, af1[ni], acc[mi][ni], 0, 0, 0);
                }
            }
        }

        // fixed scale ∀k -> rank by raw int dot (monotone ord = dot^0x80000000)
        const uint32_t metabase = (uint32_t)(it << 2);
        #pragma unroll
        for (int mi = 0; mi < 4; mi++)
            #pragma unroll
            for (int ni = 0; ni < 4; ni++) {
                const uint32_t meta = metabase | (uint32_t)ni;
                #pragma unroll
                for (int r = 0; r < 4; r++) {
                    uint32_t ord = (uint32_t)acc[mi][ni][r] ^ 0x80000000u;
                    uint32_t pk = (ord & 0xFFFFFFC0u) | meta;
                    int s = mi * 4 + r;
                    uint32_t lo = umin32(v1[s], pk);
                    v1[s] = umax32(v1[s], pk);
                    v2[s] = umax32(v2[s], lo);
                }
            }
    }

    // block top-3 per row via u32 LDS (stride 33); k reconstructed from column
    uint32_t* cl = (uint32_t*)smem;
    u64 g1 = 0, g2 = 0, g3 = 0;
    for (int pass = 0; pass < 2; pass++) {
        __syncthreads();
        #pragma unroll
        for (int s = 0; s < 16; s++) {
            int mi = s >> 2, r = s & 3;
            int row_local = wm * 64 + mi * 16 + q * 4 + r;
            cl[row_local * 33 + wn * 16 + lr] = pass ? v2[s] : v1[s];
        }
        __syncthreads();
        if (t < BT) {
            #pragma unroll 4
            for (int j = 0; j < 32; j++) {
                uint32_t pv = cl[t * 33 + j];
                uint32_t meta = pv & 63u;
                int k = (kslot + (int)(meta >> 2) * KSLOTS) * KT
                      + (j >> 4) * 64 + (int)(meta & 3u) * 16 + (j & 15);
                u64 e = ((u64)(pv & 0xFFFFFFC0u) << 32) | (u64)(~(uint32_t)k);
                u64 t1 = umax64(g1, e), t2 = umin64(g1, e);
                g3 = umax64(g3, umin64(g2, t2));
                g2 = umax64(g2, t2);
                g1 = t1;
            }
        }
    }
    if (t < BT) {
        size_t base = ((size_t)(b0 + t) * KSLOTS + kslot) * 3;
        cand[base] = g1;
        cand[base + 1] = g2;
        cand[base + 2] = g3;
    }
}

// one wave per row: top-8 of 96 candidates, exact fp32 rescore, argmax.
__global__ __launch_bounds__(256) void refine_kernel(
    const float* __restrict__ h, const float* __restrict__ A,
    const float* __restrict__ rn, const u64* __restrict__ cand,
    int* __restrict__ out)
{
    const int t = threadIdx.x, lane = t & 63, wid = t >> 6;
    const int row = blockIdx.x * 4 + wid;
    const u64* cr = cand + (size_t)row * (KSLOTS * 3);
    u64 x0 = cr[lane];                                         // 64 entries
    u64 x1 = (lane < KSLOTS * 3 - 64) ? cr[64 + lane] : 0ULL;  // 32 entries

    u64 sel[8];
    #pragma unroll
    for (int j = 0; j < 8; j++) {
        u64 v = umax64(x0, x1);
        #pragma unroll
        for (int m = 32; m >= 1; m >>= 1) v = umax64(v, __shfl_xor(v, m, 64));
        sel[j] = v;
        if (x0 == v) x0 = 0;
        else if (x1 == v) x1 = 0;
    }

    const fx4* hp = reinterpret_cast<const fx4*>(h + (size_t)row * DIM);
    fx4 h0 = hp[lane * 2], h1 = hp[lane * 2 + 1];

    u64 best = 0;
    #pragma unroll
    for (int j = 0; j < 8; j++) {
        uint32_t kg = ~(uint32_t)sel[j];
        const fx4* ap = reinterpret_cast<const fx4*>(A + (size_t)kg * DIM);
        fx4 a0 = ap[lane * 2], a1 = ap[lane * 2 + 1];
        float s = h0[0]*a0[0] + h0[1]*a0[1] + h0[2]*a0[2] + h0[3]*a0[3]
                + h1[0]*a1[0] + h1[1]*a1[1] + h1[2]*a1[2] + h1[3]*a1[3];
        #pragma unroll
        for (int m = 32; m >= 1; m >>= 1) s += __shfl_xor(s, m, 64);
        s *= rn[kg];
        u64 pk = ((u64)ford(s) << 32) | (u64)(~kg);
        best = umax64(best, pk);
    }
    if (lane == 0) out[row] = (int)(~(uint32_t)best);
}

extern "C" void kernel_launch(void* const* d_in, const int* in_sizes, int n_in,
                              void* d_out, int out_size, void* d_ws, size_t ws_size,
                              hipStream_t stream) {
    const float* h = (const float*)d_in[0];   // [4096, 512]
    const float* A = (const float*)d_in[1];   // [32768, 512]
    int* out = (int*)d_out;                   // [4096] int32

    // ws: a8 (16MB) | h8 (2MB) | rn (128KB) | cand (3MB)
    char* w = (char*)d_ws;
    char* a8 = w;
    char* h8 = w + (size_t)K_ROWS * DIM;
    float* rn = (float*)(w + (size_t)(K_ROWS + B_ROWS) * DIM);
    u64* cand = (u64*)(w + (size_t)(K_ROWS + B_ROWS) * DIM
                         + (size_t)K_ROWS * sizeof(float));

    prep_kernel<<<8192 + 1024, 256, 0, stream>>>(A, h, a8, h8, rn);
    score_kernel<<<32 * KSLOTS, 256, 0, stream>>>(h8, a8, cand);
    refine_kernel<<<B_ROWS / 4, 256, 0, stream>>>(h, A, rn, cand, out);
}

// Round 10
// 206.782 us; speedup vs baseline: 1.2673x; 1.2673x over previous
//
#include <hip/hip_runtime.h>
#include <stdint.h>

// out[b] = argmax_k cos(h_b, A_k), int32, first-index ties.
// prep: rn[k]=1/max(||A_k||,eps); a8/h8 = int8(round(x_norm * 127/0.26)) row-major.
// score: i8 MFMA 16x16x64 screen (exact int accum, fixed scale -> rank by raw
//        int dot); per-row top-3 per block -> cand[4096][32][3].
// refine: exact fp32 rescore of top-8 of 96 candidates per row.

#define DIM 512
#define B_ROWS 4096
#define K_ROWS 32768
#define BT 128
#define KT 128
#define NKT (K_ROWS / KT)    // 256
#define KSLOTS 32            // grid = 32*32 = 1024; exactly 8 k-tiles per block
#define NCHUNK 4             // D chunks of 128 bytes (i8)
#define QSCALE (127.0f / 0.26f)

typedef __attribute__((ext_vector_type(4))) float fx4;
typedef __attribute__((ext_vector_type(4))) int int4v;
typedef unsigned long long u64;

__device__ __forceinline__ uint32_t ford(float s) {
    uint32_t u = __float_as_uint(s);
    return u ^ ((uint32_t)((int32_t)u >> 31) | 0x80000000u);
}
__device__ __forceinline__ u64 umax64(u64 a, u64 b) { return a > b ? a : b; }
__device__ __forceinline__ u64 umin64(u64 a, u64 b) { return a < b ? a : b; }
__device__ __forceinline__ uint32_t umax32(uint32_t a, uint32_t b) { return a > b ? a : b; }
__device__ __forceinline__ uint32_t umin32(uint32_t a, uint32_t b) { return a < b ? a : b; }

__device__ __forceinline__ int q8(float x, float qs) {
    int v = __float2int_rn(x * qs);
    return v < -127 ? -127 : (v > 127 ? 127 : v);
}

// Fused prep: one wave per row. Blocks 0..8191 -> A rows (rn + a8);
// blocks 8192..9215 -> h rows (h8). Row-major i8, 8 bytes/lane.
__global__ __launch_bounds__(256) void prep_kernel(const float* __restrict__ A,
                                                   const float* __restrict__ h,
                                                   char* __restrict__ a8,
                                                   char* __restrict__ h8,
                                                   float* __restrict__ rn) {
    const int lane = threadIdx.x & 63, wid = threadIdx.x >> 6;
    const bool isA = blockIdx.x < 8192;
    const int row = (isA ? blockIdx.x : blockIdx.x - 8192) * 4 + wid;
    const float* src = (isA ? A : h) + (size_t)row * DIM;
    char* dst = (isA ? a8 : h8) + (size_t)row * DIM;

    const fx4* p = (const fx4*)src;
    fx4 a = p[lane * 2], b = p[lane * 2 + 1];
    float ss = a[0]*a[0] + a[1]*a[1] + a[2]*a[2] + a[3]*a[3]
             + b[0]*b[0] + b[1]*b[1] + b[2]*b[2] + b[3]*b[3];
    #pragma unroll
    for (int off = 32; off > 0; off >>= 1) ss += __shfl_xor(ss, off, 64);
    float r = 1.0f / fmaxf(sqrtf(ss), 1e-8f);
    if (isA && lane == 0) rn[row] = r;

    float qs = r * QSCALE;
    int v0 = q8(a[0], qs), v1 = q8(a[1], qs), v2 = q8(a[2], qs), v3 = q8(a[3], qs);
    int v4 = q8(b[0], qs), v5 = q8(b[1], qs), v6 = q8(b[2], qs), v7 = q8(b[3], qs);
    uint32_t lo = (uint32_t)(v0 & 255) | ((uint32_t)(v1 & 255) << 8)
                | ((uint32_t)(v2 & 255) << 16) | ((uint32_t)(v3 & 255) << 24);
    uint32_t hi = (uint32_t)(v4 & 255) | ((uint32_t)(v5 & 255) << 8)
                | ((uint32_t)(v6 & 255) << 16) | ((uint32_t)(v7 & 255) << 24);
    *reinterpret_cast<uint2*>(dst + lane * 8) = make_uint2(lo, hi);
}

typedef __attribute__((address_space(3))) uint32_t lds_u32;
typedef __attribute__((address_space(1))) const uint32_t g_u32;

// launch_bounds (256,3): VGPR budget ~170 -> natural 84 VGPR, NO spills.
// 84 VGPR + 33 KB LDS still permits 4 blocks/CU at runtime.
__global__ __launch_bounds__(256, 3) void score_kernel(
    const char* __restrict__ h8, const char* __restrict__ a8,
    u64* __restrict__ cand)
{
    // per-chunk tiles: hf [128 rows][128 B] @0, af @16384; union: u32 cl[128][33]
    __shared__ __attribute__((aligned(16))) char smem[33792];
    char* hf = smem;
    char* af = smem + 16384;

    const int t = threadIdx.x, lane = t & 63, wid = t >> 6;
    const int wm = wid >> 1, wn = wid & 1;
    const int lr = lane & 15, q = lane >> 4;
    const int btile = blockIdx.x >> 5, kslot = blockIdx.x & 31;
    const int b0 = btile * BT;

    const int srow = lane >> 3;           // row within 8-row staging group
    const int scol = (lane & 7) ^ srow;   // source granule (XOR swizzle)
    const int s7 = lr & 7;
    const int sw0 = (q ^ s7) * 16;        // K-half 0: source granule q
    const int sw1 = ((4 + q) ^ s7) * 16;  // K-half 1: source granule 4+q

    const char* hsrc = h8 + (size_t)b0 * DIM;

    uint32_t v1[16], v2[16];   // per-thread top-2 per C-row, (ord&~63)|meta
    #pragma unroll
    for (int s = 0; s < 16; s++) { v1[s] = 0u; v2[s] = 0u; }

    int it = 0;
    #pragma unroll 1
    for (int kt = kslot; kt < NKT; kt += KSLOTS, it++) {   // exactly 8 iters
        const int k0 = kt * KT;
        const char* asrc = a8 + (size_t)k0 * DIM;

        int4v acc[4][4];
        #pragma unroll
        for (int mi = 0; mi < 4; mi++)
            #pragma unroll
            for (int ni = 0; ni < 4; ni++)
                acc[mi][ni] = (int4v){0, 0, 0, 0};

        #pragma unroll 1
        for (int dc = 0; dc < NCHUNK; dc++) {
            __syncthreads();
            #pragma unroll
            for (int i = 0; i < 4; i++) {
                int issue = wid * 4 + i;
                size_t roff = (size_t)(issue * 8 + srow) * DIM + dc * 128 + scol * 16;
                __builtin_amdgcn_global_load_lds((g_u32*)(hsrc + roff),
                    (lds_u32*)(hf + issue * 1024), 16, 0, 0);
                __builtin_amdgcn_global_load_lds((g_u32*)(asrc + roff),
                    (lds_u32*)(af + issue * 1024), 16, 0, 0);
            }
            __syncthreads();

            int4v af0[4], af1[4];
            #pragma unroll
            for (int ni = 0; ni < 4; ni++) {
                const char* base = af + (wn * 64 + ni * 16 + lr) * 128;
                af0[ni] = *reinterpret_cast<const int4v*>(base + sw0);
                af1[ni] = *reinterpret_cast<const int4v*>(base + sw1);
            }
            #pragma unroll
            for (int mi = 0; mi < 4; mi++) {
                const char* base = hf + (wm * 64 + mi * 16 + lr) * 128;
                int4v h0 = *reinterpret_cast<const int4v*>(base + sw0);
                int4v h1 = *reinterpret_cast<const int4v*>(base + sw1);
                #pragma unroll
                for (int ni = 0; ni < 4; ni++) {
                    acc[mi][ni] = __builtin_amdgcn_mfma_i32_16x16x64_i8(h0, af0[ni], acc[mi][ni], 0, 0, 0);
                    acc[mi][ni] = __builtin_amdgcn_mfma_i32_16x16x64_i8(h1, af1[ni], acc[mi][ni], 0, 0, 0);
                }
            }
        }

        // fixed scale ∀k -> rank by raw int dot (monotone ord = dot^0x80000000)
        const uint32_t metabase = (uint32_t)(it << 2);
        #pragma unroll
        for (int mi = 0; mi < 4; mi++)
            #pragma unroll
            for (int ni = 0; ni < 4; ni++) {
                const uint32_t meta = metabase | (uint32_t)ni;
                #pragma unroll
                for (int r = 0; r < 4; r++) {
                    uint32_t ord = (uint32_t)acc[mi][ni][r] ^ 0x80000000u;
                    uint32_t pk = (ord & 0xFFFFFFC0u) | meta;
                    int s = mi * 4 + r;
                    uint32_t lo = umin32(v1[s], pk);
                    v1[s] = umax32(v1[s], pk);
                    v2[s] = umax32(v2[s], lo);
                }
            }
    }

    // block top-3 per row via u32 LDS (stride 33); k reconstructed from column
    uint32_t* cl = (uint32_t*)smem;
    u64 g1 = 0, g2 = 0, g3 = 0;
    for (int pass = 0; pass < 2; pass++) {
        __syncthreads();
        #pragma unroll
        for (int s = 0; s < 16; s++) {
            int mi = s >> 2, r = s & 3;
            int row_local = wm * 64 + mi * 16 + q * 4 + r;
            cl[row_local * 33 + wn * 16 + lr] = pass ? v2[s] : v1[s];
        }
        __syncthreads();
        if (t < BT) {
            #pragma unroll 4
            for (int j = 0; j < 32; j++) {
                uint32_t pv = cl[t * 33 + j];
                uint32_t meta = pv & 63u;
                int k = (kslot + (int)(meta >> 2) * KSLOTS) * KT
                      + (j >> 4) * 64 + (int)(meta & 3u) * 16 + (j & 15);
                u64 e = ((u64)(pv & 0xFFFFFFC0u) << 32) | (u64)(~(uint32_t)k);
                u64 t1 = umax64(g1, e), t2 = umin64(g1, e);
                g3 = umax64(g3, umin64(g2, t2));
                g2 = umax64(g2, t2);
                g1 = t1;
            }
        }
    }
    if (t < BT) {
        size_t base = ((size_t)(b0 + t) * KSLOTS + kslot) * 3;
        cand[base] = g1;
        cand[base + 1] = g2;
        cand[base + 2] = g3;
    }
}

// one wave per row: top-8 of 96 candidates, exact fp32 rescore, argmax.
__global__ __launch_bounds__(256) void refine_kernel(
    const float* __restrict__ h, const float* __restrict__ A,
    const float* __restrict__ rn, const u64* __restrict__ cand,
    int* __restrict__ out)
{
    const int t = threadIdx.x, lane = t & 63, wid = t >> 6;
    const int row = blockIdx.x * 4 + wid;
    const u64* cr = cand + (size_t)row * (KSLOTS * 3);
    u64 x0 = cr[lane];                                         // 64 entries
    u64 x1 = (lane < KSLOTS * 3 - 64) ? cr[64 + lane] : 0ULL;  // 32 entries

    u64 sel[8];
    #pragma unroll
    for (int j = 0; j < 8; j++) {
        u64 v = umax64(x0, x1);
        #pragma unroll
        for (int m = 32; m >= 1; m >>= 1) v = umax64(v, __shfl_xor(v, m, 64));
        sel[j] = v;
        if (x0 == v) x0 = 0;
        else if (x1 == v) x1 = 0;
    }

    const fx4* hp = reinterpret_cast<const fx4*>(h + (size_t)row * DIM);
    fx4 h0 = hp[lane * 2], h1 = hp[lane * 2 + 1];

    u64 best = 0;
    #pragma unroll
    for (int j = 0; j < 8; j++) {
        uint32_t kg = ~(uint32_t)sel[j];
        const fx4* ap = reinterpret_cast<const fx4*>(A + (size_t)kg * DIM);
        fx4 a0 = ap[lane * 2], a1 = ap[lane * 2 + 1];
        float s = h0[0]*a0[0] + h0[1]*a0[1] + h0[2]*a0[2] + h0[3]*a0[3]
                + h1[0]*a1[0] + h1[1]*a1[1] + h1[2]*a1[2] + h1[3]*a1[3];
        #pragma unroll
        for (int m = 32; m >= 1; m >>= 1) s += __shfl_xor(s, m, 64);
        s *= rn[kg];
        u64 pk = ((u64)ford(s) << 32) | (u64)(~kg);
        best = umax64(best, pk);
    }
    if (lane == 0) out[row] = (int)(~(uint32_t)best);
}

extern "C" void kernel_launch(void* const* d_in, const int* in_sizes, int n_in,
                              void* d_out, int out_size, void* d_ws, size_t ws_size,
                              hipStream_t stream) {
    const float* h = (const float*)d_in[0];   // [4096, 512]
    const float* A = (const float*)d_in[1];   // [32768, 512]
    int* out = (int*)d_out;                   // [4096] int32

    // ws: a8 (16MB) | h8 (2MB) | rn (128KB) | cand (3MB)
    char* w = (char*)d_ws;
    char* a8 = w;
    char* h8 = w + (size_t)K_ROWS * DIM;
    float* rn = (float*)(w + (size_t)(K_ROWS + B_ROWS) * DIM);
    u64* cand = (u64*)(w + (size_t)(K_ROWS + B_ROWS) * DIM
                         + (size_t)K_ROWS * sizeof(float));

    prep_kernel<<<8192 + 1024, 256, 0, stream>>>(A, h, a8, h8, rn);
    score_kernel<<<32 * KSLOTS, 256, 0, stream>>>(h8, a8, cand);
    refine_kernel<<<B_ROWS / 4, 256, 0, stream>>>(h, A, rn, cand, out);
}